// Round 4
// baseline (538.595 us; speedup 1.0000x reference)
//
#include <hip/hip_runtime.h>

typedef unsigned int u32;

// Order-preserving float<->uint mapping so we can use integer atomicMin/Max.
__device__ __forceinline__ u32 f2ord(float f) {
    u32 b = __float_as_uint(f);
    return (b & 0x80000000u) ? ~b : (b | 0x80000000u);
}
__device__ __forceinline__ float ord2f(u32 k) {
    u32 b = (k & 0x80000000u) ? (k ^ 0x80000000u) : ~k;
    return __uint_as_float(b);
}

// ---------------- Kernel A: global min/max reduction ----------------
// Streams x in ascending order, leaving the TAIL of x hottest in the
// 256 MiB Infinity Cache (x is exactly 256 MB).
__global__ __launch_bounds__(256) void minmax_kernel(const float4* __restrict__ x, int n4,
                                                     u32* __restrict__ ws) {
    float mn = INFINITY, mx = -INFINITY;
    int stride = gridDim.x * blockDim.x;
    for (int i = blockIdx.x * blockDim.x + threadIdx.x; i < n4; i += stride) {
        float4 v = x[i];
        mn = fminf(mn, fminf(fminf(v.x, v.y), fminf(v.z, v.w)));
        mx = fmaxf(mx, fmaxf(fmaxf(v.x, v.y), fmaxf(v.z, v.w)));
    }
    // wave(64) shuffle reduction
    #pragma unroll
    for (int off = 32; off > 0; off >>= 1) {
        mn = fminf(mn, __shfl_down(mn, off, 64));
        mx = fmaxf(mx, __shfl_down(mx, off, 64));
    }
    __shared__ float smn[4], smx[4];
    int wave = threadIdx.x >> 6;
    int lane = threadIdx.x & 63;
    if (lane == 0) { smn[wave] = mn; smx[wave] = mx; }
    __syncthreads();
    if (threadIdx.x == 0) {
        #pragma unroll
        for (int w = 1; w < 4; ++w) { mn = fminf(mn, smn[w]); mx = fmaxf(mx, smx[w]); }
        atomicMin(&ws[0], f2ord(mn));   // device-scope by default
        atomicMax(&ws[1], f2ord(mx));
    }
}

// ---------------- Kernel B: spline apply ----------------
// Traverses x BACKWARD: anti-LRU order. After kernel A, the tail of x is the
// most recently cached part in L3, so reading tail-first maximizes hits before
// the out-stream's evictions catch up.
__global__ __launch_bounds__(256) void apply_kernel(const float4* __restrict__ x,
                                                    const float* __restrict__ cp,
                                                    const float* __restrict__ knots,
                                                    const u32* __restrict__ ws,
                                                    float4* __restrict__ out, int n4) {
    __shared__ float sk[32];   // knots
    __shared__ float sa[32];   // control points (intercepts)
    __shared__ float sb[32];   // per-bin slope (cp[i+1]-cp[i])/(k[i+1]-k[i])
    if (threadIdx.x < 32) {
        sk[threadIdx.x] = knots[threadIdx.x];
        sa[threadIdx.x] = cp[threadIdx.x];
    }
    __syncthreads();
    if (threadIdx.x < 31) {
        int i = threadIdx.x;
        sb[i] = (sa[i + 1] - sa[i]) / (sk[i + 1] - sk[i]);
    }
    __syncthreads();

    float mn = ord2f(ws[0]);
    float mx = ord2f(ws[1]);
    float scale = 1.0f / (mx - mn + 1e-6f);
    float klo = sk[0], khi = sk[31];

    const int gtid   = blockIdx.x * blockDim.x + threadIdx.x;
    const int stride = gridDim.x * blockDim.x;
    const int KMAX   = (n4 + stride - 1) / stride;

    for (int k = KMAX - 1; k >= 0; --k) {
        const int i = k * stride + gtid;
        if (i >= n4) continue;           // only possible at k = KMAX-1
        float4 v = x[i];
        float4 r;
        float* vp = (float*)&v;
        float* rp = (float*)&r;
        #pragma unroll
        for (int c = 0; c < 4; ++c) {
            float xn = (vp[c] - mn) * scale;
            // initial bin estimate (knots ~ uniform on [0,1])
            int b = (int)(xn * 31.0f);
            b = b < 0 ? 0 : (b > 30 ? 30 : b);
            // boundary correction vs actual knot values -> searchsorted(right)-1 semantics
            if (xn < sk[b]) {
                b = (b > 0) ? b - 1 : 0;
            } else if (xn >= sk[b + 1]) {
                b = (b < 30) ? b + 1 : 30;
            }
            float val = fmaf(xn - sk[b], sb[b], sa[b]);
            rp[c] = (xn >= klo && xn <= khi) ? val : 0.0f;
        }
        out[i] = r;
    }
}

extern "C" void kernel_launch(void* const* d_in, const int* in_sizes, int n_in,
                              void* d_out, int out_size, void* d_ws, size_t ws_size,
                              hipStream_t stream) {
    const float* x     = (const float*)d_in[0];
    const float* cp    = (const float*)d_in[1];
    const float* knots = (const float*)d_in[2];
    float* out = (float*)d_out;
    u32* ws = (u32*)d_ws;

    int n  = in_sizes[0];      // 64 * 1048576, divisible by 4
    int n4 = n / 4;

    // init reduction cells: min key = 0xFFFFFFFF, max key = 0x00000000
    hipMemsetAsync(ws, 0xFF, 4, stream);
    hipMemsetAsync(ws + 1, 0x00, 4, stream);

    minmax_kernel<<<4096, 256, 0, stream>>>((const float4*)x, n4, ws);
    apply_kernel <<<8192, 256, 0, stream>>>((const float4*)x, cp, knots, ws,
                                            (float4*)out, n4);
}

// Round 5
// 510.299 us; speedup vs baseline: 1.0554x; 1.0554x over previous
//
#include <hip/hip_runtime.h>

typedef unsigned int u32;
typedef float vf4 __attribute__((ext_vector_type(4)));

__device__ __forceinline__ void nt_store4(float4* p, float4 v) {
    __builtin_nontemporal_store(*reinterpret_cast<vf4*>(&v), reinterpret_cast<vf4*>(p));
}
__device__ __forceinline__ float4 nt_load4(const float4* p) {
    vf4 t = __builtin_nontemporal_load(reinterpret_cast<const vf4*>(p));
    float4 r; r.x = t.x; r.y = t.y; r.z = t.z; r.w = t.w;
    return r;
}

// Order-preserving float<->uint mapping so we can use integer atomic max.
// min is tracked as max over the INVERTED key, so both cells init to 0
// (single 8-byte memset instead of two 4-byte ones).
__device__ __forceinline__ u32 f2ord(float f) {
    u32 b = __float_as_uint(f);
    return (b & 0x80000000u) ? ~b : (b | 0x80000000u);
}
__device__ __forceinline__ float ord2f(u32 k) {
    u32 b = (k & 0x80000000u) ? (k ^ 0x80000000u) : ~k;
    return __uint_as_float(b);
}

// ---------------- Kernel A: global min/max reduction ----------------
// Regular (temporal) loads on purpose: streams x ascending through L2/L3,
// leaving the TAIL of x hottest in the 256 MiB Infinity Cache (x is 256 MB).
__global__ __launch_bounds__(256) void minmax_kernel(const float4* __restrict__ x, int n4,
                                                     u32* __restrict__ ws) {
    float mn = INFINITY, mx = -INFINITY;
    int stride = gridDim.x * blockDim.x;
    for (int i = blockIdx.x * blockDim.x + threadIdx.x; i < n4; i += stride) {
        float4 v = x[i];
        mn = fminf(mn, fminf(fminf(v.x, v.y), fminf(v.z, v.w)));
        mx = fmaxf(mx, fmaxf(fmaxf(v.x, v.y), fmaxf(v.z, v.w)));
    }
    // wave(64) shuffle reduction
    #pragma unroll
    for (int off = 32; off > 0; off >>= 1) {
        mn = fminf(mn, __shfl_down(mn, off, 64));
        mx = fmaxf(mx, __shfl_down(mx, off, 64));
    }
    __shared__ float smn[4], smx[4];
    int wave = threadIdx.x >> 6;
    int lane = threadIdx.x & 63;
    if (lane == 0) { smn[wave] = mn; smx[wave] = mx; }
    __syncthreads();
    if (threadIdx.x == 0) {
        #pragma unroll
        for (int w = 1; w < 4; ++w) { mn = fminf(mn, smn[w]); mx = fmaxf(mx, smx[w]); }
        atomicMax(&ws[0], ~f2ord(mn));   // min via inverted key; cell inits to 0
        atomicMax(&ws[1],  f2ord(mx));   // max;                  cell inits to 0
    }
}

// ---------------- Kernel B: spline apply ----------------
// Traverses x BACKWARD (anti-LRU: tail of x is the most recently cached in L3
// after kernel A). x-loads and out-stores are NONTEMPORAL: x is single-use
// here, and the out stream must not write-allocate in the memory-side L3 and
// evict x's lines — this is the half of the experiment round 4 was missing.
__global__ __launch_bounds__(256) void apply_kernel(const float4* __restrict__ x,
                                                    const float* __restrict__ cp,
                                                    const float* __restrict__ knots,
                                                    const u32* __restrict__ ws,
                                                    float4* __restrict__ out, int n4) {
    __shared__ float sk[32];   // knots
    __shared__ float sa[32];   // control points (intercepts)
    __shared__ float sb[32];   // per-bin slope (cp[i+1]-cp[i])/(k[i+1]-k[i])
    if (threadIdx.x < 32) {
        sk[threadIdx.x] = knots[threadIdx.x];
        sa[threadIdx.x] = cp[threadIdx.x];
    }
    __syncthreads();
    if (threadIdx.x < 31) {
        int i = threadIdx.x;
        sb[i] = (sa[i + 1] - sa[i]) / (sk[i + 1] - sk[i]);
    }
    __syncthreads();

    float mn = ord2f(~ws[0]);
    float mx = ord2f(ws[1]);
    float scale = 1.0f / (mx - mn + 1e-6f);
    float klo = sk[0], khi = sk[31];

    const int gtid   = blockIdx.x * blockDim.x + threadIdx.x;
    const int stride = gridDim.x * blockDim.x;
    const int KMAX   = (n4 + stride - 1) / stride;

    for (int k = KMAX - 1; k >= 0; --k) {
        const int i = k * stride + gtid;
        if (i >= n4) continue;           // only possible at k = KMAX-1
        float4 v = nt_load4(&x[i]);
        float4 r;
        float* vp = (float*)&v;
        float* rp = (float*)&r;
        #pragma unroll
        for (int c = 0; c < 4; ++c) {
            float xn = (vp[c] - mn) * scale;
            // initial bin estimate (knots ~ uniform on [0,1])
            int b = (int)(xn * 31.0f);
            b = b < 0 ? 0 : (b > 30 ? 30 : b);
            // boundary correction vs actual knot values -> searchsorted(right)-1 semantics
            if (xn < sk[b]) {
                b = (b > 0) ? b - 1 : 0;
            } else if (xn >= sk[b + 1]) {
                b = (b < 30) ? b + 1 : 30;
            }
            float val = fmaf(xn - sk[b], sb[b], sa[b]);
            rp[c] = (xn >= klo && xn <= khi) ? val : 0.0f;
        }
        nt_store4(&out[i], r);
    }
}

extern "C" void kernel_launch(void* const* d_in, const int* in_sizes, int n_in,
                              void* d_out, int out_size, void* d_ws, size_t ws_size,
                              hipStream_t stream) {
    const float* x     = (const float*)d_in[0];
    const float* cp    = (const float*)d_in[1];
    const float* knots = (const float*)d_in[2];
    float* out = (float*)d_out;
    u32* ws = (u32*)d_ws;

    int n  = in_sizes[0];      // 64 * 1048576, divisible by 4
    int n4 = n / 4;

    // both reduction cells (inverted-min key, max key) initialize to 0
    hipMemsetAsync(ws, 0x00, 8, stream);

    minmax_kernel<<<4096, 256, 0, stream>>>((const float4*)x, n4, ws);
    apply_kernel <<<8192, 256, 0, stream>>>((const float4*)x, cp, knots, ws,
                                            (float4*)out, n4);
}